// Round 14
// baseline (322.399 us; speedup 1.0000x reference)
//
#include <hip/hip_runtime.h>
#include <math.h>

#define N_NODES 50000
#define N_EDGES 20000
#define NNZ_CT  500000
#define KDIM    256
#define K32     8

#define NB_RANK 248         // rank blocks; CHUNK*NB_RANK >= NNZ
#define CHUNK   2048        // items per rank block (pow2: b = i>>11)
#define EW      5000        // edge hist words (20000/4)
#define VW      12500       // node hist words (50000/4)
#define ESTRIDE 96          // fixed slots per edge segment
#define VSTRIDE 48          // fixed slots per node segment

typedef __attribute__((ext_vector_type(8))) short    short8v;
typedef __attribute__((ext_vector_type(4))) float    f32x4;
typedef __attribute__((ext_vector_type(8))) unsigned short ushort8v;
typedef __attribute__((ext_vector_type(4))) unsigned short ushort4v;

#define GLD16(g, l) __builtin_amdgcn_global_load_lds( \
    (const __attribute__((address_space(1))) unsigned int*)(g), \
    (__attribute__((address_space(3))) unsigned int*)(l), 16, 0, 0)

__device__ __forceinline__ unsigned short bf16_rne(float f) {
    unsigned u = __float_as_uint(f);
    return (unsigned short)((u + 0x7FFFu + ((u >> 16) & 1u)) >> 16);
}
__device__ __forceinline__ float bf16_to_f(unsigned short h) {
    return __uint_as_float(((unsigned)h) << 16);
}
__device__ __forceinline__ void bf16_split(float f, unsigned short& h, unsigned short& l) {
    unsigned u = __float_as_uint(f);
    unsigned hb = (u + 0x7FFFu + ((u >> 16) & 1u)) >> 16;
    h = (unsigned short)hb;
    float r = f - __uint_as_float(hb << 16);
    unsigned ru = __float_as_uint(r);
    l = (unsigned short)((ru + 0x7FFFu + ((ru >> 16) & 1u)) >> 16);
}
__device__ __forceinline__ void nt_store8(unsigned short* p, ushort8v v) {
    __builtin_nontemporal_store(v, (ushort8v*)p);
}

// ==== K1: LDS-histogram rank assignment, single fused pass (0 device atomics) ====
__global__ __launch_bounds__(256) void rank_lds(
    const int* __restrict__ node_idx, const int* __restrict__ edge_idx,
    unsigned* __restrict__ bhe, unsigned* __restrict__ bhv,
    unsigned char* __restrict__ lrank_e, unsigned char* __restrict__ lrank_v)
{
    __shared__ unsigned hist[EW + VW];      // 70 KB: edges [0,EW), nodes [EW,EW+VW)
    int b = blockIdx.x;
    int i0 = b * CHUNK;
    int i1 = i0 + CHUNK; if (i1 > NNZ_CT) i1 = NNZ_CT;
    for (int w = threadIdx.x; w < EW + VW; w += 256) hist[w] = 0;
    __syncthreads();
    for (int i = i0 + threadIdx.x; i < i1; i += 256) {
        int e = edge_idx[i], v = node_idx[i];
        unsigned she = 8u * (e & 3);
        unsigned olde = atomicAdd(&hist[e >> 2], 1u << she);
        lrank_e[i] = (unsigned char)((olde >> she) & 0xFFu);
        unsigned shv = 8u * (v & 3);
        unsigned oldv = atomicAdd(&hist[EW + (v >> 2)], 1u << shv);
        lrank_v[i] = (unsigned char)((oldv >> shv) & 0xFFu);
    }
    __syncthreads();
    for (int w = threadIdx.x; w < EW; w += 256) bhe[(size_t)b * EW + w] = hist[w];
    for (int w = threadIdx.x; w < VW; w += 256) bhv[(size_t)b * VW + w] = hist[EW + w];
}

// ---- device body: fp32 B[K,Ncols] -> fragment-tiled bf16 hi/lo ----
__device__ __forceinline__ void conv_B_body(
    const float* __restrict__ B, unsigned short* __restrict__ Bh,
    unsigned short* __restrict__ Bl, int Ncols, int n16_count, int t)
{
    if (t >= n16_count * 512) return;
    int lane = t & 63, k32 = (t >> 6) & 7, n16 = t >> 9;
    int col = n16 * 16 + (lane & 15);
    int k0  = k32 * 32 + (lane >> 4) * 8;
    ushort8v h, l;
#pragma unroll
    for (int j = 0; j < 8; j++) {
        float f = (col < Ncols) ? B[(size_t)(k0 + j) * Ncols + col] : 0.f;
        unsigned short hh, ll; bf16_split(f, hh, ll); h[j] = hh; l[j] = ll;
    }
    size_t off = (((size_t)n16 * 8 + k32) << 9) + lane * 8;
    *(ushort8v*)(Bh + off) = h;
    *(ushort8v*)(Bl + off) = l;
}

// ==== K2: fused {cross-block bases + cnt + invdeg} + {convert X} + {convert W1/2/3} ====
// blocks [0,69): bases; [69,6319): convX; [6319,6399): convW
__global__ __launch_bounds__(256) void mid_fuse(
    const unsigned* __restrict__ bhe, const unsigned* __restrict__ bhv,
    unsigned* __restrict__ bbase_e, unsigned* __restrict__ bbase_v,
    int* __restrict__ cnt_e, int* __restrict__ cnt_v,
    float* __restrict__ inv_e, float* __restrict__ inv_v,
    const float* __restrict__ X, unsigned short* __restrict__ Xb,
    const float* __restrict__ W1, unsigned short* __restrict__ W1h, unsigned short* __restrict__ W1l,
    const float* __restrict__ W2, unsigned short* __restrict__ W2h, unsigned short* __restrict__ W2l,
    const float* __restrict__ W3, unsigned short* __restrict__ W3h, unsigned short* __restrict__ W3l)
{
    int b0 = blockIdx.x;
    if (b0 < 69) {
        int t = b0 * 256 + threadIdx.x;
        if (t >= EW + VW) return;
        const unsigned* bh; unsigned* bb; int* cnt; float* inv; int w; int stride;
        if (t < EW) { bh = bhe; bb = bbase_e; cnt = cnt_e; inv = inv_e; w = t; stride = EW; }
        else        { bh = bhv; bb = bbase_v; cnt = cnt_v; inv = inv_v; w = t - EW; stride = VW; }
        unsigned s0 = 0, s1 = 0, s2 = 0, s3 = 0;
#pragma unroll 2
        for (int b = 0; b < NB_RANK; ++b) {
            unsigned h = bh[(size_t)b * stride + w];
            bb[(size_t)b * stride + w] = s0 | (s1 << 8) | (s2 << 16) | (s3 << 24);
            s0 += h & 255u; s1 += (h >> 8) & 255u; s2 += (h >> 16) & 255u; s3 += (h >> 24);
        }
        *(int4*)(cnt + 4 * w) = make_int4((int)s0, (int)s1, (int)s2, (int)s3);
        float4 iv;
        iv.x = 1.0f / fmaxf((float)s0, 1.0f);
        iv.y = 1.0f / fmaxf((float)s1, 1.0f);
        iv.z = 1.0f / fmaxf((float)s2, 1.0f);
        iv.w = 1.0f / fmaxf((float)s3, 1.0f);
        *(float4*)(inv + 4 * w) = iv;
    } else if (b0 < 6319) {
        int t = (b0 - 69) * 256 + threadIdx.x;      // < 1.6M exact
        const float* src = X + (size_t)t * 8;
        float f[8];
        *(float4*)(f)     = *(const float4*)(src);
        *(float4*)(f + 4) = *(const float4*)(src + 4);
        ushort8v h;
#pragma unroll
        for (int j = 0; j < 8; j++) h[j] = bf16_rne(f[j]);
        nt_store8(Xb + (size_t)t * 8, h);
    } else {
        int j = b0 - 6319;
        if (j < 32)      conv_B_body(W1, W1h, W1l, 256, 16, j * 256 + (int)threadIdx.x);
        else if (j < 64) conv_B_body(W2, W2h, W2l, 256, 16, (j - 32) * 256 + (int)threadIdx.x);
        else             conv_B_body(W3, W3h, W3l, 40,  8,  (j - 64) * 256 + (int)threadIdx.x);
    }
}

// ==== K3: atomic-free key-partitioned CSR fill, fixed-stride segments ====
__global__ __launch_bounds__(256) void fill_part(
    const int* __restrict__ node_idx, const int* __restrict__ edge_idx,
    const unsigned char* __restrict__ lrank_e, const unsigned char* __restrict__ lrank_v,
    const unsigned* __restrict__ bbase_e, const unsigned* __restrict__ bbase_v,
    int* __restrict__ csr_e_nodes, int* __restrict__ csr_v_edges)
{
    int part = blockIdx.x & 7, blk = blockIdx.x >> 3, nblk = gridDim.x >> 3;
    int elo = part * (N_EDGES / 8), ehi = elo + N_EDGES / 8;
    int vlo = part * (N_NODES / 8), vhi = vlo + N_NODES / 8;
    for (int i = blk * 256 + threadIdx.x; i < NNZ_CT; i += nblk * 256) {
        int e = edge_idx[i], v = node_idx[i];
        int b = i >> 11;                    // i / CHUNK
        if (e >= elo && e < ehi) {
            unsigned bb = (bbase_e[(size_t)b * EW + (e >> 2)] >> (8u * (e & 3))) & 0xFFu;
            csr_e_nodes[e * ESTRIDE + (int)bb + (int)lrank_e[i]] = v;
        }
        if (v >= vlo && v < vhi) {
            unsigned bb = (bbase_v[(size_t)b * VW + (v >> 2)] >> (8u * (v & 3))) & 0xFFu;
            csr_v_edges[v * VSTRIDE + (int)bb + (int)lrank_v[i]] = e;
        }
    }
}

// ---- MFMA GEMM: A tiled bf16, B tiled split hi/lo; C bf16 row-major ----
__global__ __launch_bounds__(256) void gemm_bf16(
    const unsigned short* __restrict__ At,
    const unsigned short* __restrict__ Bh, const unsigned short* __restrict__ Bl,
    unsigned short* __restrict__ C, int M, int Ncols, int ldC)
{
    __shared__ unsigned short lds[16384];
    const int tid  = threadIdx.x;
    const int lane = tid & 63, wid = tid >> 6;
    const int wr = wid >> 1, wc = wid & 1;
    const int m0t = blockIdx.y * 8;
    const int n0t = blockIdx.x * 8;

    f32x4 acc[4][4] = {};

    for (int k32 = 0; k32 < K32; ++k32) {
#pragma unroll
        for (int i = 0; i < 6; ++i) {
            int c = i * 4 + wid;               // 0..23
            if (c < 8) {
                const unsigned short* gA = At + (((size_t)(m0t + c) * 8 + k32) << 9) + lane * 8;
                GLD16(gA, &lds[c * 512 + lane * 8]);
            } else {
                int idx = c - 8, half = idx >> 3, st = idx & 7;
                const unsigned short* gB = (half ? Bl : Bh)
                    + (((size_t)(n0t + st) * 8 + k32) << 9) + lane * 8;
                GLD16(gB, &lds[4096 + idx * 512 + lane * 8]);
            }
        }
        __syncthreads();
        short8v a[4], bh[4], bl[4];
#pragma unroll
        for (int x = 0; x < 4; ++x) {
            a[x]  = *(const short8v*)&lds[(wr * 4 + x) * 512 + lane * 8];
            bh[x] = *(const short8v*)&lds[4096 + (wc * 4 + x) * 512 + lane * 8];
            bl[x] = *(const short8v*)&lds[4096 + (8 + wc * 4 + x) * 512 + lane * 8];
        }
#pragma unroll
        for (int mi = 0; mi < 4; ++mi)
#pragma unroll
            for (int ni = 0; ni < 4; ++ni) {
                acc[mi][ni] = __builtin_amdgcn_mfma_f32_16x16x32_bf16(a[mi], bh[ni], acc[mi][ni], 0, 0, 0);
                acc[mi][ni] = __builtin_amdgcn_mfma_f32_16x16x32_bf16(a[mi], bl[ni], acc[mi][ni], 0, 0, 0);
            }
        __syncthreads();
    }

    {
        const int rg = lane >> 4, cl = lane & 15;
        const int base = wid * 4096;
#pragma unroll
        for (int mi = 0; mi < 4; ++mi) {
            int swz = ((mi * 4 + rg) & 3) << 4;
#pragma unroll
            for (int ni = 0; ni < 4; ++ni) {
                int colf = (ni * 16 + cl) ^ swz;
#pragma unroll
                for (int r = 0; r < 4; ++r)
                    lds[base + (mi * 16 + rg * 4 + r) * 64 + colf] = bf16_rne(acc[mi][ni][r]);
            }
        }
    }
    __syncthreads();
    {
        int row = tid >> 1, half = tid & 1;
        int grow = blockIdx.y * 128 + row;
        if (grow < M) {
            int wsrc = (row >> 6) * 2 + half;
            int rl = row & 63;
            int swz = ((rl >> 2) & 3) << 4;
            unsigned short* dst = C + (size_t)grow * ldC + n0t * 16 + half * 64;
#pragma unroll
            for (int s = 0; s < 8; ++s) {
                int c0 = half * 64 + s * 8;
                if (n0t * 16 + c0 + 8 <= Ncols) {
                    ushort8v v = *(const ushort8v*)&lds[wsrc * 4096 + rl * 64 + ((s * 8) ^ swz)];
                    nt_store8(dst + s * 8, v);
                }
            }
        }
    }
}

// ---- V->E mean (256-dim) -> fragment-tiled bf16; 512 thr, one edge per half-wave ----
__global__ __launch_bounds__(512) void agg_e256_tiled(
    const unsigned short* __restrict__ src, unsigned short* __restrict__ Et,
    const int* __restrict__ cnt, const int* __restrict__ lists,
    const float* __restrict__ invdeg)
{
    __shared__ unsigned short hbuf[16 * 264];
    int tid = threadIdx.x, lane = tid & 31, hw = tid >> 5;   // hw: 0..15
    int e16 = blockIdx.x;
    {
        int el = hw;
        int w = e16 * 16 + el;
        int s = w * ESTRIDE, e = s + cnt[w];
        float a[8] = {};
        for (int j = s; j < e; j += 8) {
            int r[8]; float m[8];
            r[0] = lists[j]; m[0] = 1.f;
#pragma unroll
            for (int u = 1; u < 8; ++u) {
                bool ok = (j + u) < e;
                r[u] = ok ? lists[j + u] : r[0];
                m[u] = ok ? 1.f : 0.f;
            }
            ushort8v v[8];
#pragma unroll
            for (int u = 0; u < 8; ++u)
                v[u] = *(const ushort8v*)(src + (size_t)r[u] * 256 + lane * 8);
#pragma unroll
            for (int k = 0; k < 8; ++k) a[k] += bf16_to_f(v[0][k]);
#pragma unroll
            for (int u = 1; u < 8; ++u)
#pragma unroll
                for (int k = 0; k < 8; ++k)
                    a[k] = fmaf(m[u], bf16_to_f(v[u][k]), a[k]);
        }
        float sc = invdeg[w];
        ushort8v o;
#pragma unroll
        for (int k = 0; k < 8; ++k) o[k] = bf16_rne(a[k] * sc);
        *(ushort8v*)&hbuf[el * 264 + lane * 8] = o;
    }
    __syncthreads();
    {
        int sl = tid;                      // 0..511
        int k32 = sl >> 6, lt = sl & 63;
        int row = lt & 15, hi = lt >> 4;
        int k0 = k32 * 32 + hi * 8;
        ushort8v v = *(const ushort8v*)&hbuf[row * 264 + k0];
        nt_store8(Et + (((size_t)e16 * 8 + k32) << 9) + lt * 8, v);
    }
}

// ---- E->V mean + bias + relu -> row-major bf16; half-wave per node ----
__global__ __launch_bounds__(256) void agg_v256_row(
    const unsigned short* __restrict__ src, unsigned short* __restrict__ Vb,
    const int* __restrict__ cnt, const int* __restrict__ lists,
    const float* __restrict__ invdeg, const float* __restrict__ bias, int nseg)
{
    int w = (blockIdx.x * 256 + threadIdx.x) >> 5;
    int lane = threadIdx.x & 31;
    if (w >= nseg) return;
    int s = w * VSTRIDE, e = s + cnt[w];
    float a[8] = {};
    for (int j = s; j < e; j += 8) {
        int r[8]; float m[8];
        r[0] = lists[j]; m[0] = 1.f;
#pragma unroll
        for (int u = 1; u < 8; ++u) {
            bool ok = (j + u) < e;
            r[u] = ok ? lists[j + u] : r[0];
            m[u] = ok ? 1.f : 0.f;
        }
        ushort8v v[8];
#pragma unroll
        for (int u = 0; u < 8; ++u)
            v[u] = *(const ushort8v*)(src + (size_t)r[u] * 256 + lane * 8);
#pragma unroll
        for (int k = 0; k < 8; ++k) a[k] += bf16_to_f(v[0][k]);
#pragma unroll
        for (int u = 1; u < 8; ++u)
#pragma unroll
            for (int k = 0; k < 8; ++k)
                a[k] = fmaf(m[u], bf16_to_f(v[u][k]), a[k]);
    }
    float sc = invdeg[w];
    float4 b0 = *(const float4*)(bias + lane * 8);
    float4 b1 = *(const float4*)(bias + lane * 8 + 4);
    float bb[8] = { b0.x, b0.y, b0.z, b0.w, b1.x, b1.y, b1.z, b1.w };
    ushort8v o;
#pragma unroll
    for (int k = 0; k < 8; ++k) o[k] = bf16_rne(fmaxf(a[k] * sc + bb[k], 0.f));
    nt_store8(Vb + (size_t)w * 256 + lane * 8, o);
}

// ---- E->V mean + bias + relu -> fragment-tiled bf16; 512 thr, one node per half-wave ----
__global__ __launch_bounds__(512) void agg_v256_blk(
    const unsigned short* __restrict__ src, unsigned short* __restrict__ At,
    const int* __restrict__ cnt, const int* __restrict__ lists,
    const float* __restrict__ invdeg, const float* __restrict__ bias)
{
    __shared__ unsigned short hbuf[16 * 264];
    int tid = threadIdx.x, lane = tid & 31, hw = tid >> 5;   // hw: 0..15
    int m16 = blockIdx.x;
    float4 b0 = *(const float4*)(bias + lane * 8);
    float4 b1 = *(const float4*)(bias + lane * 8 + 4);
    float bb[8] = { b0.x, b0.y, b0.z, b0.w, b1.x, b1.y, b1.z, b1.w };
    {
        int nl = hw;
        int w = m16 * 16 + nl;
        int s = w * VSTRIDE, e = s + cnt[w];
        float a[8] = {};
        for (int j = s; j < e; j += 8) {
            int r[8]; float m[8];
            r[0] = lists[j]; m[0] = 1.f;
#pragma unroll
            for (int u = 1; u < 8; ++u) {
                bool ok = (j + u) < e;
                r[u] = ok ? lists[j + u] : r[0];
                m[u] = ok ? 1.f : 0.f;
            }
            ushort8v v[8];
#pragma unroll
            for (int u = 0; u < 8; ++u)
                v[u] = *(const ushort8v*)(src + (size_t)r[u] * 256 + lane * 8);
#pragma unroll
            for (int k = 0; k < 8; ++k) a[k] += bf16_to_f(v[0][k]);
#pragma unroll
            for (int u = 1; u < 8; ++u)
#pragma unroll
                for (int k = 0; k < 8; ++k)
                    a[k] = fmaf(m[u], bf16_to_f(v[u][k]), a[k]);
        }
        float sc = invdeg[w];
        ushort8v o;
#pragma unroll
        for (int k = 0; k < 8; ++k) o[k] = bf16_rne(fmaxf(a[k] * sc + bb[k], 0.f));
        *(ushort8v*)&hbuf[nl * 264 + lane * 8] = o;
    }
    __syncthreads();
    {
        int sl = tid;                      // 0..511
        int k32 = sl >> 6, lt = sl & 63;
        int row = lt & 15, hi = lt >> 4;
        int k0 = k32 * 32 + hi * 8;
        ushort8v v = *(const ushort8v*)&hbuf[row * 264 + k0];
        nt_store8(At + (((size_t)m16 * 8 + k32) << 9) + lt * 8, v);
    }
}

// ---- mean-aggregation, F=40 (edges), bf16 in, bf16 out, 8 in flight ----
__global__ __launch_bounds__(256) void agg_mean40(
    const unsigned short* __restrict__ src, unsigned short* __restrict__ dst,
    const int* __restrict__ cnt, const int* __restrict__ lists,
    const float* __restrict__ invdeg, int nseg)
{
    int w = (blockIdx.x * 256 + threadIdx.x) >> 6;
    int lane = threadIdx.x & 63;
    if (w >= nseg) return;
    int s = w * ESTRIDE, e = s + cnt[w];
    if (lane < 40) {
        float acc = 0.f;
        for (int j = s; j < e; j += 8) {
            int r[8]; float m[8];
            r[0] = lists[j]; m[0] = 1.f;
#pragma unroll
            for (int u = 1; u < 8; ++u) {
                bool ok = (j + u) < e;
                r[u] = ok ? lists[j + u] : r[0];
                m[u] = ok ? 1.f : 0.f;
            }
            float v[8];
#pragma unroll
            for (int u = 0; u < 8; ++u)
                v[u] = bf16_to_f(src[(size_t)r[u] * 40 + lane]);
            acc += v[0];
#pragma unroll
            for (int u = 1; u < 8; ++u) acc = fmaf(m[u], v[u], acc);
        }
        dst[(size_t)w * 40 + lane] = bf16_rne(acc * invdeg[w]);
    }
}

// ------- final E->V mean at F=40 + bias + log_softmax, wave per node -------
__global__ __launch_bounds__(256) void agg_v40_lsm(
    const unsigned short* __restrict__ efeat, float* __restrict__ out,
    const int* __restrict__ cnt, const int* __restrict__ lists,
    const float* __restrict__ invdeg, const float* __restrict__ bias,
    int nseg)
{
    int w = (blockIdx.x * 256 + threadIdx.x) >> 6;
    int lane = threadIdx.x & 63;
    if (w >= nseg) return;
    int s = w * VSTRIDE, e = s + cnt[w];
    float acc = 0.f;
    if (lane < 40) {
        for (int j = s; j < e; j += 4) {
            int r[4]; float m[4];
            r[0] = lists[j]; m[0] = 1.f;
#pragma unroll
            for (int u = 1; u < 4; ++u) {
                bool ok = (j + u) < e;
                r[u] = ok ? lists[j + u] : r[0];
                m[u] = ok ? 1.f : 0.f;
            }
            float v[4];
#pragma unroll
            for (int u = 0; u < 4; ++u)
                v[u] = bf16_to_f(efeat[(size_t)r[u] * 40 + lane]);
            acc += v[0];
#pragma unroll
            for (int u = 1; u < 4; ++u) acc = fmaf(m[u], v[u], acc);
        }
    }
    float val = (lane < 40) ? (acc * invdeg[w] + bias[lane]) : -1e30f;
    float m = val;
#pragma unroll
    for (int o = 32; o; o >>= 1) m = fmaxf(m, __shfl_xor(m, o));
    float ex = (lane < 40) ? expf(val - m) : 0.f;
    float ssum = ex;
#pragma unroll
    for (int o = 32; o; o >>= 1) ssum += __shfl_xor(ssum, o);
    if (lane < 40) out[(size_t)w * 40 + lane] = val - m - logf(ssum);
}

// ---------------- launch ----------------
extern "C" void kernel_launch(void* const* d_in, const int* in_sizes, int n_in,
                              void* d_out, int out_size, void* d_ws, size_t ws_size,
                              hipStream_t stream)
{
    const float* X        = (const float*)d_in[0];
    const int*   node_idx = (const int*)d_in[1];
    const int*   edge_idx = (const int*)d_in[2];
    const float* W1 = (const float*)d_in[3];
    const float* b1 = (const float*)d_in[4];
    const float* W2 = (const float*)d_in[5];
    const float* b2 = (const float*)d_in[6];
    const float* W3 = (const float*)d_in[7];
    const float* b3 = (const float*)d_in[8];
    float* out = (float*)d_out;

    char* p = (char*)d_ws;
    auto alloc = [&](size_t bytes) -> char* {
        char* r = p;
        p += (bytes + 255) & ~(size_t)255;
        return r;
    };
    int*   cnt_e = (int*)alloc((size_t)N_EDGES * 4);
    int*   cnt_v = (int*)alloc((size_t)N_NODES * 4);
    float* inv_e = (float*)alloc((size_t)N_EDGES * 4);
    float* inv_v = (float*)alloc((size_t)N_NODES * 4);
    unsigned* bhe = (unsigned*)alloc((size_t)NB_RANK * EW * 4);
    unsigned* bhv = (unsigned*)alloc((size_t)NB_RANK * VW * 4);
    unsigned* bbase_e = (unsigned*)alloc((size_t)NB_RANK * EW * 4);
    unsigned* bbase_v = (unsigned*)alloc((size_t)NB_RANK * VW * 4);
    unsigned char* lrank_e = (unsigned char*)alloc((size_t)NNZ_CT);
    unsigned char* lrank_v = (unsigned char*)alloc((size_t)NNZ_CT);
    int*   csr_e = (int*)alloc((size_t)N_EDGES * ESTRIDE * 4);
    int*   csr_v = (int*)alloc((size_t)N_NODES * VSTRIDE * 4);

    const int M16 = N_NODES / 16;              // 3125
    const int M16_PAD = 391 * 8;               // 3128 (GEMM-V grid coverage)
    const int E16 = N_EDGES / 16;              // 1250
    const int E16_PAD = 157 * 8;               // 1256 (GEMM-E grid coverage)
    unsigned short* Xb  = (unsigned short*)alloc((size_t)N_NODES * 256 * 2);
    unsigned short* At  = (unsigned short*)alloc((size_t)M16_PAD * 4096 * 2);
    unsigned short* Et  = (unsigned short*)alloc((size_t)E16_PAD * 4096 * 2);
    unsigned short* Ef  = (unsigned short*)alloc((size_t)N_EDGES * 256 * 2);
    unsigned short* W1h = (unsigned short*)alloc((size_t)16 * 4096 * 2);
    unsigned short* W1l = (unsigned short*)alloc((size_t)16 * 4096 * 2);
    unsigned short* W2h = (unsigned short*)alloc((size_t)16 * 4096 * 2);
    unsigned short* W2l = (unsigned short*)alloc((size_t)16 * 4096 * 2);
    unsigned short* W3h = (unsigned short*)alloc((size_t)8 * 4096 * 2);
    unsigned short* W3l = (unsigned short*)alloc((size_t)8 * 4096 * 2);
    unsigned short* C40 = (unsigned short*)alloc((size_t)N_NODES * 40 * 2);
    unsigned short* E40 = (unsigned short*)alloc((size_t)N_EDGES * 40 * 2);

    // CSR build: fused LDS-hist ranks (248 CUs) -> bases+cnt+inv+converts -> fixed-stride fill
    rank_lds<<<NB_RANK, 256, 0, stream>>>(node_idx, edge_idx, bhe, bhv, lrank_e, lrank_v);
    mid_fuse<<<6399, 256, 0, stream>>>(bhe, bhv, bbase_e, bbase_v, cnt_e, cnt_v, inv_e, inv_v,
                                       X, Xb, W1, W1h, W1l, W2, W2h, W2l, W3, W3h, W3l);
    fill_part<<<2048, 256, 0, stream>>>(node_idx, edge_idx, lrank_e, lrank_v,
                                        bbase_e, bbase_v, csr_e, csr_v);

    dim3 gE_gemm(2, 157);    // GEMM on 20000 edge rows
    dim3 gV_gemm(1, 391);    // GEMM on 50000 node rows (layer 3, 40 cols)
    const int gVhw = (N_NODES + 7) / 8;    // half-wave row kernel: 8 segs/block
    const int gEw = (N_EDGES + 3) / 4;
    const int gVw = (N_NODES + 3) / 4;

    // layer 1: V->E agg first (commutes with GEMM), GEMM on edges, E->V to row-major
    agg_e256_tiled<<<E16, 512, 0, stream>>>(Xb, Et, cnt_e, csr_e, inv_e);
    gemm_bf16<<<gE_gemm, 256, 0, stream>>>(Et, W1h, W1l, Ef, N_EDGES, 256, 256);
    agg_v256_row<<<gVhw, 256, 0, stream>>>(Ef, Xb, cnt_v, csr_v, inv_v, b1, N_NODES);

    // layer 2: same; E->V writes tiled (feeds layer-3 GEMM-V)
    agg_e256_tiled<<<E16, 512, 0, stream>>>(Xb, Et, cnt_e, csr_e, inv_e);
    gemm_bf16<<<gE_gemm, 256, 0, stream>>>(Et, W2h, W2l, Ef, N_EDGES, 256, 256);
    agg_v256_blk<<<M16, 512, 0, stream>>>(Ef, At, cnt_v, csr_v, inv_v, b2);

    // layer 3: GEMM-V to 40 cols, then 40-dim aggs + log_softmax
    gemm_bf16<<<gV_gemm, 256, 0, stream>>>(At, W3h, W3l, C40, N_NODES, 40, 40);
    agg_mean40<<<gEw, 256, 0, stream>>>(C40, E40, cnt_e, csr_e, inv_e, N_EDGES);
    agg_v40_lsm<<<gVw, 256, 0, stream>>>(E40, out, cnt_v, csr_v, inv_v, b3, N_NODES);
    (void)in_sizes; (void)n_in; (void)out_size; (void)ws_size;
}

// Round 15
// 293.496 us; speedup vs baseline: 1.0985x; 1.0985x over previous
//
#include <hip/hip_runtime.h>
#include <math.h>

#define N_NODES 50000
#define N_EDGES 20000
#define NNZ_CT  500000
#define KDIM    256
#define K32     8

#define NB_RANK 124         // rank blocks; CHUNK*NB_RANK >= NNZ
#define CHUNK   4096        // items per rank block (pow2: b = i>>12)
#define EW      5000        // edge hist words (20000/4)
#define VW      12500       // node hist words (50000/4)
#define ESTRIDE 96          // fixed slots per edge segment
#define VSTRIDE 48          // fixed slots per node segment

typedef __attribute__((ext_vector_type(8))) short    short8v;
typedef __attribute__((ext_vector_type(4))) float    f32x4;
typedef __attribute__((ext_vector_type(8))) unsigned short ushort8v;
typedef __attribute__((ext_vector_type(4))) unsigned short ushort4v;

#define GLD16(g, l) __builtin_amdgcn_global_load_lds( \
    (const __attribute__((address_space(1))) unsigned int*)(g), \
    (__attribute__((address_space(3))) unsigned int*)(l), 16, 0, 0)

__device__ __forceinline__ unsigned short bf16_rne(float f) {
    unsigned u = __float_as_uint(f);
    return (unsigned short)((u + 0x7FFFu + ((u >> 16) & 1u)) >> 16);
}
__device__ __forceinline__ float bf16_to_f(unsigned short h) {
    return __uint_as_float(((unsigned)h) << 16);
}
__device__ __forceinline__ void bf16_split(float f, unsigned short& h, unsigned short& l) {
    unsigned u = __float_as_uint(f);
    unsigned hb = (u + 0x7FFFu + ((u >> 16) & 1u)) >> 16;
    h = (unsigned short)hb;
    float r = f - __uint_as_float(hb << 16);
    unsigned ru = __float_as_uint(r);
    l = (unsigned short)((ru + 0x7FFFu + ((ru >> 16) & 1u)) >> 16);
}
__device__ __forceinline__ void nt_store8(unsigned short* p, ushort8v v) {
    __builtin_nontemporal_store(v, (ushort8v*)p);
}

// ==== K1: LDS-histogram rank assignment, 512 threads, single fused pass ====
__global__ __launch_bounds__(512) void rank_lds(
    const int* __restrict__ node_idx, const int* __restrict__ edge_idx,
    unsigned* __restrict__ bhe, unsigned* __restrict__ bhv,
    unsigned char* __restrict__ lrank_e, unsigned char* __restrict__ lrank_v)
{
    __shared__ unsigned hist[EW + VW];      // 70 KB: edges [0,EW), nodes [EW,EW+VW)
    int b = blockIdx.x;
    int i0 = b * CHUNK;
    int i1 = i0 + CHUNK; if (i1 > NNZ_CT) i1 = NNZ_CT;
    for (int w = threadIdx.x; w < EW + VW; w += 512) hist[w] = 0;
    __syncthreads();
    for (int i = i0 + threadIdx.x; i < i1; i += 512) {
        int e = edge_idx[i], v = node_idx[i];
        unsigned she = 8u * (e & 3);
        unsigned olde = atomicAdd(&hist[e >> 2], 1u << she);
        lrank_e[i] = (unsigned char)((olde >> she) & 0xFFu);
        unsigned shv = 8u * (v & 3);
        unsigned oldv = atomicAdd(&hist[EW + (v >> 2)], 1u << shv);
        lrank_v[i] = (unsigned char)((oldv >> shv) & 0xFFu);
    }
    __syncthreads();
    for (int w = threadIdx.x; w < EW; w += 512) bhe[(size_t)b * EW + w] = hist[w];
    for (int w = threadIdx.x; w < VW; w += 512) bhv[(size_t)b * VW + w] = hist[EW + w];
}

// ---- device body: fp32 B[K,Ncols] -> fragment-tiled bf16 hi/lo ----
__device__ __forceinline__ void conv_B_body(
    const float* __restrict__ B, unsigned short* __restrict__ Bh,
    unsigned short* __restrict__ Bl, int Ncols, int n16_count, int t)
{
    if (t >= n16_count * 512) return;
    int lane = t & 63, k32 = (t >> 6) & 7, n16 = t >> 9;
    int col = n16 * 16 + (lane & 15);
    int k0  = k32 * 32 + (lane >> 4) * 8;
    ushort8v h, l;
#pragma unroll
    for (int j = 0; j < 8; j++) {
        float f = (col < Ncols) ? B[(size_t)(k0 + j) * Ncols + col] : 0.f;
        unsigned short hh, ll; bf16_split(f, hh, ll); h[j] = hh; l[j] = ll;
    }
    size_t off = (((size_t)n16 * 8 + k32) << 9) + lane * 8;
    *(ushort8v*)(Bh + off) = h;
    *(ushort8v*)(Bl + off) = l;
}

// ==== K2: fused {cross-block bases + cnt + invdeg} + {convert X} + {convert W1/2/3} ====
// blocks [0,69): bases; [69,6319): convX; [6319,6399): convW
__global__ __launch_bounds__(256) void mid_fuse(
    const unsigned* __restrict__ bhe, const unsigned* __restrict__ bhv,
    unsigned* __restrict__ bbase_e, unsigned* __restrict__ bbase_v,
    int* __restrict__ cnt_e, int* __restrict__ cnt_v,
    float* __restrict__ inv_e, float* __restrict__ inv_v,
    const float* __restrict__ X, unsigned short* __restrict__ Xb,
    const float* __restrict__ W1, unsigned short* __restrict__ W1h, unsigned short* __restrict__ W1l,
    const float* __restrict__ W2, unsigned short* __restrict__ W2h, unsigned short* __restrict__ W2l,
    const float* __restrict__ W3, unsigned short* __restrict__ W3h, unsigned short* __restrict__ W3l)
{
    int b0 = blockIdx.x;
    if (b0 < 69) {
        int t = b0 * 256 + threadIdx.x;
        if (t >= EW + VW) return;
        const unsigned* bh; unsigned* bb; int* cnt; float* inv; int w; int stride;
        if (t < EW) { bh = bhe; bb = bbase_e; cnt = cnt_e; inv = inv_e; w = t; stride = EW; }
        else        { bh = bhv; bb = bbase_v; cnt = cnt_v; inv = inv_v; w = t - EW; stride = VW; }
        unsigned s0 = 0, s1 = 0, s2 = 0, s3 = 0;
#pragma unroll 4
        for (int b = 0; b < NB_RANK; ++b) {
            unsigned h = bh[(size_t)b * stride + w];
            bb[(size_t)b * stride + w] = s0 | (s1 << 8) | (s2 << 16) | (s3 << 24);
            s0 += h & 255u; s1 += (h >> 8) & 255u; s2 += (h >> 16) & 255u; s3 += (h >> 24);
        }
        *(int4*)(cnt + 4 * w) = make_int4((int)s0, (int)s1, (int)s2, (int)s3);
        float4 iv;
        iv.x = 1.0f / fmaxf((float)s0, 1.0f);
        iv.y = 1.0f / fmaxf((float)s1, 1.0f);
        iv.z = 1.0f / fmaxf((float)s2, 1.0f);
        iv.w = 1.0f / fmaxf((float)s3, 1.0f);
        *(float4*)(inv + 4 * w) = iv;
    } else if (b0 < 6319) {
        int t = (b0 - 69) * 256 + threadIdx.x;      // < 1.6M exact
        const float* src = X + (size_t)t * 8;
        float f[8];
        *(float4*)(f)     = *(const float4*)(src);
        *(float4*)(f + 4) = *(const float4*)(src + 4);
        ushort8v h;
#pragma unroll
        for (int j = 0; j < 8; j++) h[j] = bf16_rne(f[j]);
        nt_store8(Xb + (size_t)t * 8, h);
    } else {
        int j = b0 - 6319;
        if (j < 32)      conv_B_body(W1, W1h, W1l, 256, 16, j * 256 + (int)threadIdx.x);
        else if (j < 64) conv_B_body(W2, W2h, W2l, 256, 16, (j - 32) * 256 + (int)threadIdx.x);
        else             conv_B_body(W3, W3h, W3l, 40,  8,  (j - 64) * 256 + (int)threadIdx.x);
    }
}

// ==== K3: atomic-free key-partitioned CSR fill, fixed-stride segments ====
__global__ __launch_bounds__(256) void fill_part(
    const int* __restrict__ node_idx, const int* __restrict__ edge_idx,
    const unsigned char* __restrict__ lrank_e, const unsigned char* __restrict__ lrank_v,
    const unsigned* __restrict__ bbase_e, const unsigned* __restrict__ bbase_v,
    int* __restrict__ csr_e_nodes, int* __restrict__ csr_v_edges)
{
    int part = blockIdx.x & 7, blk = blockIdx.x >> 3, nblk = gridDim.x >> 3;
    int elo = part * (N_EDGES / 8), ehi = elo + N_EDGES / 8;
    int vlo = part * (N_NODES / 8), vhi = vlo + N_NODES / 8;
    for (int i = blk * 256 + threadIdx.x; i < NNZ_CT; i += nblk * 256) {
        int e = edge_idx[i], v = node_idx[i];
        int b = i >> 12;                    // i / CHUNK
        if (e >= elo && e < ehi) {
            unsigned bb = (bbase_e[(size_t)b * EW + (e >> 2)] >> (8u * (e & 3))) & 0xFFu;
            csr_e_nodes[e * ESTRIDE + (int)bb + (int)lrank_e[i]] = v;
        }
        if (v >= vlo && v < vhi) {
            unsigned bb = (bbase_v[(size_t)b * VW + (v >> 2)] >> (8u * (v & 3))) & 0xFFu;
            csr_v_edges[v * VSTRIDE + (int)bb + (int)lrank_v[i]] = e;
        }
    }
}

// ---- MFMA GEMM: A tiled bf16, B tiled split hi/lo; C bf16 row-major ----
__global__ __launch_bounds__(256) void gemm_bf16(
    const unsigned short* __restrict__ At,
    const unsigned short* __restrict__ Bh, const unsigned short* __restrict__ Bl,
    unsigned short* __restrict__ C, int M, int Ncols, int ldC)
{
    __shared__ unsigned short lds[16384];
    const int tid  = threadIdx.x;
    const int lane = tid & 63, wid = tid >> 6;
    const int wr = wid >> 1, wc = wid & 1;
    const int m0t = blockIdx.y * 8;
    const int n0t = blockIdx.x * 8;

    f32x4 acc[4][4] = {};

    for (int k32 = 0; k32 < K32; ++k32) {
#pragma unroll
        for (int i = 0; i < 6; ++i) {
            int c = i * 4 + wid;               // 0..23
            if (c < 8) {
                const unsigned short* gA = At + (((size_t)(m0t + c) * 8 + k32) << 9) + lane * 8;
                GLD16(gA, &lds[c * 512 + lane * 8]);
            } else {
                int idx = c - 8, half = idx >> 3, st = idx & 7;
                const unsigned short* gB = (half ? Bl : Bh)
                    + (((size_t)(n0t + st) * 8 + k32) << 9) + lane * 8;
                GLD16(gB, &lds[4096 + idx * 512 + lane * 8]);
            }
        }
        __syncthreads();
        short8v a[4], bh[4], bl[4];
#pragma unroll
        for (int x = 0; x < 4; ++x) {
            a[x]  = *(const short8v*)&lds[(wr * 4 + x) * 512 + lane * 8];
            bh[x] = *(const short8v*)&lds[4096 + (wc * 4 + x) * 512 + lane * 8];
            bl[x] = *(const short8v*)&lds[4096 + (8 + wc * 4 + x) * 512 + lane * 8];
        }
#pragma unroll
        for (int mi = 0; mi < 4; ++mi)
#pragma unroll
            for (int ni = 0; ni < 4; ++ni) {
                acc[mi][ni] = __builtin_amdgcn_mfma_f32_16x16x32_bf16(a[mi], bh[ni], acc[mi][ni], 0, 0, 0);
                acc[mi][ni] = __builtin_amdgcn_mfma_f32_16x16x32_bf16(a[mi], bl[ni], acc[mi][ni], 0, 0, 0);
            }
        __syncthreads();
    }

    {
        const int rg = lane >> 4, cl = lane & 15;
        const int base = wid * 4096;
#pragma unroll
        for (int mi = 0; mi < 4; ++mi) {
            int swz = ((mi * 4 + rg) & 3) << 4;
#pragma unroll
            for (int ni = 0; ni < 4; ++ni) {
                int colf = (ni * 16 + cl) ^ swz;
#pragma unroll
                for (int r = 0; r < 4; ++r)
                    lds[base + (mi * 16 + rg * 4 + r) * 64 + colf] = bf16_rne(acc[mi][ni][r]);
            }
        }
    }
    __syncthreads();
    {
        int row = tid >> 1, half = tid & 1;
        int grow = blockIdx.y * 128 + row;
        if (grow < M) {
            int wsrc = (row >> 6) * 2 + half;
            int rl = row & 63;
            int swz = ((rl >> 2) & 3) << 4;
            unsigned short* dst = C + (size_t)grow * ldC + n0t * 16 + half * 64;
#pragma unroll
            for (int s = 0; s < 8; ++s) {
                int c0 = half * 64 + s * 8;
                if (n0t * 16 + c0 + 8 <= Ncols) {
                    ushort8v v = *(const ushort8v*)&lds[wsrc * 4096 + rl * 64 + ((s * 8) ^ swz)];
                    nt_store8(dst + s * 8, v);
                }
            }
        }
    }
}

// ---- V->E mean (256-dim) -> fragment-tiled bf16; 512 thr, one edge per half-wave ----
__global__ __launch_bounds__(512) void agg_e256_tiled(
    const unsigned short* __restrict__ src, unsigned short* __restrict__ Et,
    const int* __restrict__ cnt, const int* __restrict__ lists,
    const float* __restrict__ invdeg)
{
    __shared__ unsigned short hbuf[16 * 264];
    int tid = threadIdx.x, lane = tid & 31, hw = tid >> 5;   // hw: 0..15
    int e16 = blockIdx.x;
    {
        int el = hw;
        int w = e16 * 16 + el;
        int s = w * ESTRIDE, e = s + cnt[w];
        float a[8] = {};
        for (int j = s; j < e; j += 8) {
            int r[8]; float m[8];
            r[0] = lists[j]; m[0] = 1.f;
#pragma unroll
            for (int u = 1; u < 8; ++u) {
                bool ok = (j + u) < e;
                r[u] = ok ? lists[j + u] : r[0];
                m[u] = ok ? 1.f : 0.f;
            }
            ushort8v v[8];
#pragma unroll
            for (int u = 0; u < 8; ++u)
                v[u] = *(const ushort8v*)(src + (size_t)r[u] * 256 + lane * 8);
#pragma unroll
            for (int k = 0; k < 8; ++k) a[k] += bf16_to_f(v[0][k]);
#pragma unroll
            for (int u = 1; u < 8; ++u)
#pragma unroll
                for (int k = 0; k < 8; ++k)
                    a[k] = fmaf(m[u], bf16_to_f(v[u][k]), a[k]);
        }
        float sc = invdeg[w];
        ushort8v o;
#pragma unroll
        for (int k = 0; k < 8; ++k) o[k] = bf16_rne(a[k] * sc);
        *(ushort8v*)&hbuf[el * 264 + lane * 8] = o;
    }
    __syncthreads();
    {
        int sl = tid;                      // 0..511
        int k32 = sl >> 6, lt = sl & 63;
        int row = lt & 15, hi = lt >> 4;
        int k0 = k32 * 32 + hi * 8;
        ushort8v v = *(const ushort8v*)&hbuf[row * 264 + k0];
        nt_store8(Et + (((size_t)e16 * 8 + k32) << 9) + lt * 8, v);
    }
}

// ---- E->V mean + bias + relu -> row-major bf16; half-wave per node ----
__global__ __launch_bounds__(256) void agg_v256_row(
    const unsigned short* __restrict__ src, unsigned short* __restrict__ Vb,
    const int* __restrict__ cnt, const int* __restrict__ lists,
    const float* __restrict__ invdeg, const float* __restrict__ bias, int nseg)
{
    int w = (blockIdx.x * 256 + threadIdx.x) >> 5;
    int lane = threadIdx.x & 31;
    if (w >= nseg) return;
    int s = w * VSTRIDE, e = s + cnt[w];
    float a[8] = {};
    for (int j = s; j < e; j += 8) {
        int r[8]; float m[8];
        r[0] = lists[j]; m[0] = 1.f;
#pragma unroll
        for (int u = 1; u < 8; ++u) {
            bool ok = (j + u) < e;
            r[u] = ok ? lists[j + u] : r[0];
            m[u] = ok ? 1.f : 0.f;
        }
        ushort8v v[8];
#pragma unroll
        for (int u = 0; u < 8; ++u)
            v[u] = *(const ushort8v*)(src + (size_t)r[u] * 256 + lane * 8);
#pragma unroll
        for (int k = 0; k < 8; ++k) a[k] += bf16_to_f(v[0][k]);
#pragma unroll
        for (int u = 1; u < 8; ++u)
#pragma unroll
            for (int k = 0; k < 8; ++k)
                a[k] = fmaf(m[u], bf16_to_f(v[u][k]), a[k]);
    }
    float sc = invdeg[w];
    float4 b0 = *(const float4*)(bias + lane * 8);
    float4 b1 = *(const float4*)(bias + lane * 8 + 4);
    float bb[8] = { b0.x, b0.y, b0.z, b0.w, b1.x, b1.y, b1.z, b1.w };
    ushort8v o;
#pragma unroll
    for (int k = 0; k < 8; ++k) o[k] = bf16_rne(fmaxf(a[k] * sc + bb[k], 0.f));
    nt_store8(Vb + (size_t)w * 256 + lane * 8, o);
}

// ---- E->V mean + bias + relu -> fragment-tiled bf16; 512 thr, one node per half-wave ----
__global__ __launch_bounds__(512) void agg_v256_blk(
    const unsigned short* __restrict__ src, unsigned short* __restrict__ At,
    const int* __restrict__ cnt, const int* __restrict__ lists,
    const float* __restrict__ invdeg, const float* __restrict__ bias)
{
    __shared__ unsigned short hbuf[16 * 264];
    int tid = threadIdx.x, lane = tid & 31, hw = tid >> 5;   // hw: 0..15
    int m16 = blockIdx.x;
    float4 b0 = *(const float4*)(bias + lane * 8);
    float4 b1 = *(const float4*)(bias + lane * 8 + 4);
    float bb[8] = { b0.x, b0.y, b0.z, b0.w, b1.x, b1.y, b1.z, b1.w };
    {
        int nl = hw;
        int w = m16 * 16 + nl;
        int s = w * VSTRIDE, e = s + cnt[w];
        float a[8] = {};
        for (int j = s; j < e; j += 8) {
            int r[8]; float m[8];
            r[0] = lists[j]; m[0] = 1.f;
#pragma unroll
            for (int u = 1; u < 8; ++u) {
                bool ok = (j + u) < e;
                r[u] = ok ? lists[j + u] : r[0];
                m[u] = ok ? 1.f : 0.f;
            }
            ushort8v v[8];
#pragma unroll
            for (int u = 0; u < 8; ++u)
                v[u] = *(const ushort8v*)(src + (size_t)r[u] * 256 + lane * 8);
#pragma unroll
            for (int k = 0; k < 8; ++k) a[k] += bf16_to_f(v[0][k]);
#pragma unroll
            for (int u = 1; u < 8; ++u)
#pragma unroll
                for (int k = 0; k < 8; ++k)
                    a[k] = fmaf(m[u], bf16_to_f(v[u][k]), a[k]);
        }
        float sc = invdeg[w];
        ushort8v o;
#pragma unroll
        for (int k = 0; k < 8; ++k) o[k] = bf16_rne(fmaxf(a[k] * sc + bb[k], 0.f));
        *(ushort8v*)&hbuf[nl * 264 + lane * 8] = o;
    }
    __syncthreads();
    {
        int sl = tid;                      // 0..511
        int k32 = sl >> 6, lt = sl & 63;
        int row = lt & 15, hi = lt >> 4;
        int k0 = k32 * 32 + hi * 8;
        ushort8v v = *(const ushort8v*)&hbuf[row * 264 + k0];
        nt_store8(At + (((size_t)m16 * 8 + k32) << 9) + lt * 8, v);
    }
}

// ---- mean-aggregation, F=40 (edges), bf16 in, bf16 out, 8 in flight ----
__global__ __launch_bounds__(256) void agg_mean40(
    const unsigned short* __restrict__ src, unsigned short* __restrict__ dst,
    const int* __restrict__ cnt, const int* __restrict__ lists,
    const float* __restrict__ invdeg, int nseg)
{
    int w = (blockIdx.x * 256 + threadIdx.x) >> 6;
    int lane = threadIdx.x & 63;
    if (w >= nseg) return;
    int s = w * ESTRIDE, e = s + cnt[w];
    if (lane < 40) {
        float acc = 0.f;
        for (int j = s; j < e; j += 8) {
            int r[8]; float m[8];
            r[0] = lists[j]; m[0] = 1.f;
#pragma unroll
            for (int u = 1; u < 8; ++u) {
                bool ok = (j + u) < e;
                r[u] = ok ? lists[j + u] : r[0];
                m[u] = ok ? 1.f : 0.f;
            }
            float v[8];
#pragma unroll
            for (int u = 0; u < 8; ++u)
                v[u] = bf16_to_f(src[(size_t)r[u] * 40 + lane]);
            acc += v[0];
#pragma unroll
            for (int u = 1; u < 8; ++u) acc = fmaf(m[u], v[u], acc);
        }
        dst[(size_t)w * 40 + lane] = bf16_rne(acc * invdeg[w]);
    }
}

// ------- final E->V mean at F=40 + bias + log_softmax, wave per node -------
__global__ __launch_bounds__(256) void agg_v40_lsm(
    const unsigned short* __restrict__ efeat, float* __restrict__ out,
    const int* __restrict__ cnt, const int* __restrict__ lists,
    const float* __restrict__ invdeg, const float* __restrict__ bias,
    int nseg)
{
    int w = (blockIdx.x * 256 + threadIdx.x) >> 6;
    int lane = threadIdx.x & 63;
    if (w >= nseg) return;
    int s = w * VSTRIDE, e = s + cnt[w];
    float acc = 0.f;
    if (lane < 40) {
        for (int j = s; j < e; j += 4) {
            int r[4]; float m[4];
            r[0] = lists[j]; m[0] = 1.f;
#pragma unroll
            for (int u = 1; u < 4; ++u) {
                bool ok = (j + u) < e;
                r[u] = ok ? lists[j + u] : r[0];
                m[u] = ok ? 1.f : 0.f;
            }
            float v[4];
#pragma unroll
            for (int u = 0; u < 4; ++u)
                v[u] = bf16_to_f(efeat[(size_t)r[u] * 40 + lane]);
            acc += v[0];
#pragma unroll
            for (int u = 1; u < 4; ++u) acc = fmaf(m[u], v[u], acc);
        }
    }
    float val = (lane < 40) ? (acc * invdeg[w] + bias[lane]) : -1e30f;
    float m = val;
#pragma unroll
    for (int o = 32; o; o >>= 1) m = fmaxf(m, __shfl_xor(m, o));
    float ex = (lane < 40) ? expf(val - m) : 0.f;
    float ssum = ex;
#pragma unroll
    for (int o = 32; o; o >>= 1) ssum += __shfl_xor(ssum, o);
    if (lane < 40) out[(size_t)w * 40 + lane] = val - m - logf(ssum);
}

// ---------------- launch ----------------
extern "C" void kernel_launch(void* const* d_in, const int* in_sizes, int n_in,
                              void* d_out, int out_size, void* d_ws, size_t ws_size,
                              hipStream_t stream)
{
    const float* X        = (const float*)d_in[0];
    const int*   node_idx = (const int*)d_in[1];
    const int*   edge_idx = (const int*)d_in[2];
    const float* W1 = (const float*)d_in[3];
    const float* b1 = (const float*)d_in[4];
    const float* W2 = (const float*)d_in[5];
    const float* b2 = (const float*)d_in[6];
    const float* W3 = (const float*)d_in[7];
    const float* b3 = (const float*)d_in[8];
    float* out = (float*)d_out;

    char* p = (char*)d_ws;
    auto alloc = [&](size_t bytes) -> char* {
        char* r = p;
        p += (bytes + 255) & ~(size_t)255;
        return r;
    };
    int*   cnt_e = (int*)alloc((size_t)N_EDGES * 4);
    int*   cnt_v = (int*)alloc((size_t)N_NODES * 4);
    float* inv_e = (float*)alloc((size_t)N_EDGES * 4);
    float* inv_v = (float*)alloc((size_t)N_NODES * 4);
    unsigned* bhe = (unsigned*)alloc((size_t)NB_RANK * EW * 4);
    unsigned* bhv = (unsigned*)alloc((size_t)NB_RANK * VW * 4);
    unsigned* bbase_e = (unsigned*)alloc((size_t)NB_RANK * EW * 4);
    unsigned* bbase_v = (unsigned*)alloc((size_t)NB_RANK * VW * 4);
    unsigned char* lrank_e = (unsigned char*)alloc((size_t)NNZ_CT);
    unsigned char* lrank_v = (unsigned char*)alloc((size_t)NNZ_CT);
    int*   csr_e = (int*)alloc((size_t)N_EDGES * ESTRIDE * 4);
    int*   csr_v = (int*)alloc((size_t)N_NODES * VSTRIDE * 4);

    const int M16 = N_NODES / 16;              // 3125
    const int M16_PAD = 391 * 8;               // 3128 (GEMM-V grid coverage)
    const int E16 = N_EDGES / 16;              // 1250
    const int E16_PAD = 157 * 8;               // 1256 (GEMM-E grid coverage)
    unsigned short* Xb  = (unsigned short*)alloc((size_t)N_NODES * 256 * 2);
    unsigned short* At  = (unsigned short*)alloc((size_t)M16_PAD * 4096 * 2);
    unsigned short* Et  = (unsigned short*)alloc((size_t)E16_PAD * 4096 * 2);
    unsigned short* Ef  = (unsigned short*)alloc((size_t)N_EDGES * 256 * 2);
    unsigned short* W1h = (unsigned short*)alloc((size_t)16 * 4096 * 2);
    unsigned short* W1l = (unsigned short*)alloc((size_t)16 * 4096 * 2);
    unsigned short* W2h = (unsigned short*)alloc((size_t)16 * 4096 * 2);
    unsigned short* W2l = (unsigned short*)alloc((size_t)16 * 4096 * 2);
    unsigned short* W3h = (unsigned short*)alloc((size_t)8 * 4096 * 2);
    unsigned short* W3l = (unsigned short*)alloc((size_t)8 * 4096 * 2);
    unsigned short* C40 = (unsigned short*)alloc((size_t)N_NODES * 40 * 2);
    unsigned short* E40 = (unsigned short*)alloc((size_t)N_EDGES * 40 * 2);

    // CSR build: 512-thread LDS-hist ranks -> bases+cnt+inv+converts -> fixed-stride fill
    rank_lds<<<NB_RANK, 512, 0, stream>>>(node_idx, edge_idx, bhe, bhv, lrank_e, lrank_v);
    mid_fuse<<<6399, 256, 0, stream>>>(bhe, bhv, bbase_e, bbase_v, cnt_e, cnt_v, inv_e, inv_v,
                                       X, Xb, W1, W1h, W1l, W2, W2h, W2l, W3, W3h, W3l);
    fill_part<<<2048, 256, 0, stream>>>(node_idx, edge_idx, lrank_e, lrank_v,
                                        bbase_e, bbase_v, csr_e, csr_v);

    dim3 gE_gemm(2, 157);    // GEMM on 20000 edge rows
    dim3 gV_gemm(1, 391);    // GEMM on 50000 node rows (layer 3, 40 cols)
    const int gVhw = (N_NODES + 7) / 8;    // half-wave row kernel: 8 segs/block
    const int gEw = (N_EDGES + 3) / 4;
    const int gVw = (N_NODES + 3) / 4;

    // layer 1: V->E agg first (commutes with GEMM), GEMM on edges, E->V to row-major
    agg_e256_tiled<<<E16, 512, 0, stream>>>(Xb, Et, cnt_e, csr_e, inv_e);
    gemm_bf16<<<gE_gemm, 256, 0, stream>>>(Et, W1h, W1l, Ef, N_EDGES, 256, 256);
    agg_v256_row<<<gVhw, 256, 0, stream>>>(Ef, Xb, cnt_v, csr_v, inv_v, b1, N_NODES);

    // layer 2: same; E->V writes tiled (feeds layer-3 GEMM-V)
    agg_e256_tiled<<<E16, 512, 0, stream>>>(Xb, Et, cnt_e, csr_e, inv_e);
    gemm_bf16<<<gE_gemm, 256, 0, stream>>>(Et, W2h, W2l, Ef, N_EDGES, 256, 256);
    agg_v256_blk<<<M16, 512, 0, stream>>>(Ef, At, cnt_v, csr_v, inv_v, b2);

    // layer 3: GEMM-V to 40 cols, then 40-dim aggs + log_softmax
    gemm_bf16<<<gV_gemm, 256, 0, stream>>>(At, W3h, W3l, C40, N_NODES, 40, 40);
    agg_mean40<<<gEw, 256, 0, stream>>>(C40, E40, cnt_e, csr_e, inv_e, N_EDGES);
    agg_v40_lsm<<<gVw, 256, 0, stream>>>(E40, out, cnt_v, csr_v, inv_v, b3, N_NODES);
    (void)in_sizes; (void)n_in; (void)out_size; (void)ws_size;
}

// Round 16
// 290.071 us; speedup vs baseline: 1.1114x; 1.0118x over previous
//
#include <hip/hip_runtime.h>
#include <math.h>

#define N_NODES 50000
#define N_EDGES 20000
#define NNZ_CT  500000
#define KDIM    256
#define K32     8

#define NB_RANK 128         // rank blocks (mult of 8 for batched scan); CHUNK*NB_RANK >= NNZ
#define CHUNK   4096        // items per rank block (pow2: b = i>>12)
#define EW      5000        // edge hist words (20000/4)
#define VW      12500       // node hist words (50000/4)
#define ESTRIDE 96          // fixed slots per edge segment
#define VSTRIDE 48          // fixed slots per node segment

typedef __attribute__((ext_vector_type(8))) short    short8v;
typedef __attribute__((ext_vector_type(4))) float    f32x4;
typedef __attribute__((ext_vector_type(8))) unsigned short ushort8v;
typedef __attribute__((ext_vector_type(4))) unsigned short ushort4v;

#define GLD16(g, l) __builtin_amdgcn_global_load_lds( \
    (const __attribute__((address_space(1))) unsigned int*)(g), \
    (__attribute__((address_space(3))) unsigned int*)(l), 16, 0, 0)

__device__ __forceinline__ unsigned short bf16_rne(float f) {
    unsigned u = __float_as_uint(f);
    return (unsigned short)((u + 0x7FFFu + ((u >> 16) & 1u)) >> 16);
}
__device__ __forceinline__ float bf16_to_f(unsigned short h) {
    return __uint_as_float(((unsigned)h) << 16);
}
__device__ __forceinline__ void bf16_split(float f, unsigned short& h, unsigned short& l) {
    unsigned u = __float_as_uint(f);
    unsigned hb = (u + 0x7FFFu + ((u >> 16) & 1u)) >> 16;
    h = (unsigned short)hb;
    float r = f - __uint_as_float(hb << 16);
    unsigned ru = __float_as_uint(r);
    l = (unsigned short)((ru + 0x7FFFu + ((ru >> 16) & 1u)) >> 16);
}
__device__ __forceinline__ void nt_store8(unsigned short* p, ushort8v v) {
    __builtin_nontemporal_store(v, (ushort8v*)p);
}

// ==== K1: LDS-histogram rank assignment, 512 threads, single fused pass ====
__global__ __launch_bounds__(512) void rank_lds(
    const int* __restrict__ node_idx, const int* __restrict__ edge_idx,
    unsigned* __restrict__ bhe, unsigned* __restrict__ bhv,
    unsigned char* __restrict__ lrank_e, unsigned char* __restrict__ lrank_v)
{
    __shared__ unsigned hist[EW + VW];      // 70 KB: edges [0,EW), nodes [EW,EW+VW)
    int b = blockIdx.x;
    int i0 = b * CHUNK;
    int i1 = i0 + CHUNK; if (i1 > NNZ_CT) i1 = NNZ_CT;
    for (int w = threadIdx.x; w < EW + VW; w += 512) hist[w] = 0;
    __syncthreads();
    for (int i = i0 + threadIdx.x; i < i1; i += 512) {
        int e = edge_idx[i], v = node_idx[i];
        unsigned she = 8u * (e & 3);
        unsigned olde = atomicAdd(&hist[e >> 2], 1u << she);
        lrank_e[i] = (unsigned char)((olde >> she) & 0xFFu);
        unsigned shv = 8u * (v & 3);
        unsigned oldv = atomicAdd(&hist[EW + (v >> 2)], 1u << shv);
        lrank_v[i] = (unsigned char)((oldv >> shv) & 0xFFu);
    }
    __syncthreads();
    for (int w = threadIdx.x; w < EW; w += 512) bhe[(size_t)b * EW + w] = hist[w];
    for (int w = threadIdx.x; w < VW; w += 512) bhv[(size_t)b * VW + w] = hist[EW + w];
}

// ---- device body: fp32 B[K,Ncols] -> fragment-tiled bf16 hi/lo ----
__device__ __forceinline__ void conv_B_body(
    const float* __restrict__ B, unsigned short* __restrict__ Bh,
    unsigned short* __restrict__ Bl, int Ncols, int n16_count, int t)
{
    if (t >= n16_count * 512) return;
    int lane = t & 63, k32 = (t >> 6) & 7, n16 = t >> 9;
    int col = n16 * 16 + (lane & 15);
    int k0  = k32 * 32 + (lane >> 4) * 8;
    ushort8v h, l;
#pragma unroll
    for (int j = 0; j < 8; j++) {
        float f = (col < Ncols) ? B[(size_t)(k0 + j) * Ncols + col] : 0.f;
        unsigned short hh, ll; bf16_split(f, hh, ll); h[j] = hh; l[j] = ll;
    }
    size_t off = (((size_t)n16 * 8 + k32) << 9) + lane * 8;
    *(ushort8v*)(Bh + off) = h;
    *(ushort8v*)(Bl + off) = l;
}

// ==== K2: fused {cross-block bases + cnt + invdeg} + {convert X} + {convert W1/2/3} ====
// blocks [0,69): bases; [69,6319): convX; [6319,6399): convW
__global__ __launch_bounds__(256) void mid_fuse(
    const unsigned* __restrict__ bhe, const unsigned* __restrict__ bhv,
    unsigned* __restrict__ bbase_e, unsigned* __restrict__ bbase_v,
    int* __restrict__ cnt_e, int* __restrict__ cnt_v,
    float* __restrict__ inv_e, float* __restrict__ inv_v,
    const float* __restrict__ X, unsigned short* __restrict__ Xb,
    const float* __restrict__ W1, unsigned short* __restrict__ W1h, unsigned short* __restrict__ W1l,
    const float* __restrict__ W2, unsigned short* __restrict__ W2h, unsigned short* __restrict__ W2l,
    const float* __restrict__ W3, unsigned short* __restrict__ W3h, unsigned short* __restrict__ W3l)
{
    int b0 = blockIdx.x;
    if (b0 < 69) {
        int t = b0 * 256 + threadIdx.x;
        if (t >= EW + VW) return;
        const unsigned* bh; unsigned* bb; int* cnt; float* inv; int w; int stride;
        if (t < EW) { bh = bhe; bb = bbase_e; cnt = cnt_e; inv = inv_e; w = t; stride = EW; }
        else        { bh = bhv; bb = bbase_v; cnt = cnt_v; inv = inv_v; w = t - EW; stride = VW; }
        unsigned s0 = 0, s1 = 0, s2 = 0, s3 = 0;
        // batched: 8 independent loads in flight, then 8 accumulate+store steps
        for (int bb0 = 0; bb0 < NB_RANK; bb0 += 8) {
            unsigned h[8];
#pragma unroll
            for (int k = 0; k < 8; ++k)
                h[k] = bh[(size_t)(bb0 + k) * stride + w];
#pragma unroll
            for (int k = 0; k < 8; ++k) {
                bb[(size_t)(bb0 + k) * stride + w] = s0 | (s1 << 8) | (s2 << 16) | (s3 << 24);
                s0 += h[k] & 255u; s1 += (h[k] >> 8) & 255u;
                s2 += (h[k] >> 16) & 255u; s3 += (h[k] >> 24);
            }
        }
        *(int4*)(cnt + 4 * w) = make_int4((int)s0, (int)s1, (int)s2, (int)s3);
        float4 iv;
        iv.x = 1.0f / fmaxf((float)s0, 1.0f);
        iv.y = 1.0f / fmaxf((float)s1, 1.0f);
        iv.z = 1.0f / fmaxf((float)s2, 1.0f);
        iv.w = 1.0f / fmaxf((float)s3, 1.0f);
        *(float4*)(inv + 4 * w) = iv;
    } else if (b0 < 6319) {
        int t = (b0 - 69) * 256 + threadIdx.x;      // < 1.6M exact
        const float* src = X + (size_t)t * 8;
        float f[8];
        *(float4*)(f)     = *(const float4*)(src);
        *(float4*)(f + 4) = *(const float4*)(src + 4);
        ushort8v h;
#pragma unroll
        for (int j = 0; j < 8; j++) h[j] = bf16_rne(f[j]);
        nt_store8(Xb + (size_t)t * 8, h);
    } else {
        int j = b0 - 6319;
        if (j < 32)      conv_B_body(W1, W1h, W1l, 256, 16, j * 256 + (int)threadIdx.x);
        else if (j < 64) conv_B_body(W2, W2h, W2l, 256, 16, (j - 32) * 256 + (int)threadIdx.x);
        else             conv_B_body(W3, W3h, W3l, 40,  8,  (j - 64) * 256 + (int)threadIdx.x);
    }
}

// ==== K3: atomic-free key-partitioned CSR fill, fixed-stride segments ====
__global__ __launch_bounds__(256) void fill_part(
    const int* __restrict__ node_idx, const int* __restrict__ edge_idx,
    const unsigned char* __restrict__ lrank_e, const unsigned char* __restrict__ lrank_v,
    const unsigned* __restrict__ bbase_e, const unsigned* __restrict__ bbase_v,
    int* __restrict__ csr_e_nodes, int* __restrict__ csr_v_edges)
{
    int part = blockIdx.x & 7, blk = blockIdx.x >> 3, nblk = gridDim.x >> 3;
    int elo = part * (N_EDGES / 8), ehi = elo + N_EDGES / 8;
    int vlo = part * (N_NODES / 8), vhi = vlo + N_NODES / 8;
    for (int i = blk * 256 + threadIdx.x; i < NNZ_CT; i += nblk * 256) {
        int e = edge_idx[i], v = node_idx[i];
        int b = i >> 12;                    // i / CHUNK
        if (e >= elo && e < ehi) {
            unsigned bb = (bbase_e[(size_t)b * EW + (e >> 2)] >> (8u * (e & 3))) & 0xFFu;
            csr_e_nodes[e * ESTRIDE + (int)bb + (int)lrank_e[i]] = v;
        }
        if (v >= vlo && v < vhi) {
            unsigned bb = (bbase_v[(size_t)b * VW + (v >> 2)] >> (8u * (v & 3))) & 0xFFu;
            csr_v_edges[v * VSTRIDE + (int)bb + (int)lrank_v[i]] = e;
        }
    }
}

// ---- MFMA GEMM: A tiled bf16, B tiled split hi/lo; C bf16 row-major ----
__global__ __launch_bounds__(256) void gemm_bf16(
    const unsigned short* __restrict__ At,
    const unsigned short* __restrict__ Bh, const unsigned short* __restrict__ Bl,
    unsigned short* __restrict__ C, int M, int Ncols, int ldC)
{
    __shared__ unsigned short lds[16384];
    const int tid  = threadIdx.x;
    const int lane = tid & 63, wid = tid >> 6;
    const int wr = wid >> 1, wc = wid & 1;
    const int m0t = blockIdx.y * 8;
    const int n0t = blockIdx.x * 8;

    f32x4 acc[4][4] = {};

    for (int k32 = 0; k32 < K32; ++k32) {
#pragma unroll
        for (int i = 0; i < 6; ++i) {
            int c = i * 4 + wid;               // 0..23
            if (c < 8) {
                const unsigned short* gA = At + (((size_t)(m0t + c) * 8 + k32) << 9) + lane * 8;
                GLD16(gA, &lds[c * 512 + lane * 8]);
            } else {
                int idx = c - 8, half = idx >> 3, st = idx & 7;
                const unsigned short* gB = (half ? Bl : Bh)
                    + (((size_t)(n0t + st) * 8 + k32) << 9) + lane * 8;
                GLD16(gB, &lds[4096 + idx * 512 + lane * 8]);
            }
        }
        __syncthreads();
        short8v a[4], bh[4], bl[4];
#pragma unroll
        for (int x = 0; x < 4; ++x) {
            a[x]  = *(const short8v*)&lds[(wr * 4 + x) * 512 + lane * 8];
            bh[x] = *(const short8v*)&lds[4096 + (wc * 4 + x) * 512 + lane * 8];
            bl[x] = *(const short8v*)&lds[4096 + (8 + wc * 4 + x) * 512 + lane * 8];
        }
#pragma unroll
        for (int mi = 0; mi < 4; ++mi)
#pragma unroll
            for (int ni = 0; ni < 4; ++ni) {
                acc[mi][ni] = __builtin_amdgcn_mfma_f32_16x16x32_bf16(a[mi], bh[ni], acc[mi][ni], 0, 0, 0);
                acc[mi][ni] = __builtin_amdgcn_mfma_f32_16x16x32_bf16(a[mi], bl[ni], acc[mi][ni], 0, 0, 0);
            }
        __syncthreads();
    }

    {
        const int rg = lane >> 4, cl = lane & 15;
        const int base = wid * 4096;
#pragma unroll
        for (int mi = 0; mi < 4; ++mi) {
            int swz = ((mi * 4 + rg) & 3) << 4;
#pragma unroll
            for (int ni = 0; ni < 4; ++ni) {
                int colf = (ni * 16 + cl) ^ swz;
#pragma unroll
                for (int r = 0; r < 4; ++r)
                    lds[base + (mi * 16 + rg * 4 + r) * 64 + colf] = bf16_rne(acc[mi][ni][r]);
            }
        }
    }
    __syncthreads();
    {
        int row = tid >> 1, half = tid & 1;
        int grow = blockIdx.y * 128 + row;
        if (grow < M) {
            int wsrc = (row >> 6) * 2 + half;
            int rl = row & 63;
            int swz = ((rl >> 2) & 3) << 4;
            unsigned short* dst = C + (size_t)grow * ldC + n0t * 16 + half * 64;
#pragma unroll
            for (int s = 0; s < 8; ++s) {
                int c0 = half * 64 + s * 8;
                if (n0t * 16 + c0 + 8 <= Ncols) {
                    ushort8v v = *(const ushort8v*)&lds[wsrc * 4096 + rl * 64 + ((s * 8) ^ swz)];
                    nt_store8(dst + s * 8, v);
                }
            }
        }
    }
}

// ---- V->E mean (256-dim) -> fragment-tiled bf16; 512 thr, one edge per half-wave ----
__global__ __launch_bounds__(512) void agg_e256_tiled(
    const unsigned short* __restrict__ src, unsigned short* __restrict__ Et,
    const int* __restrict__ cnt, const int* __restrict__ lists,
    const float* __restrict__ invdeg)
{
    __shared__ unsigned short hbuf[16 * 264];
    int tid = threadIdx.x, lane = tid & 31, hw = tid >> 5;   // hw: 0..15
    int e16 = blockIdx.x;
    {
        int el = hw;
        int w = e16 * 16 + el;
        int s = w * ESTRIDE, e = s + cnt[w];
        float a[8] = {};
        for (int j = s; j < e; j += 8) {
            int r[8]; float m[8];
            r[0] = lists[j]; m[0] = 1.f;
#pragma unroll
            for (int u = 1; u < 8; ++u) {
                bool ok = (j + u) < e;
                r[u] = ok ? lists[j + u] : r[0];
                m[u] = ok ? 1.f : 0.f;
            }
            ushort8v v[8];
#pragma unroll
            for (int u = 0; u < 8; ++u)
                v[u] = *(const ushort8v*)(src + (size_t)r[u] * 256 + lane * 8);
#pragma unroll
            for (int k = 0; k < 8; ++k) a[k] += bf16_to_f(v[0][k]);
#pragma unroll
            for (int u = 1; u < 8; ++u)
#pragma unroll
                for (int k = 0; k < 8; ++k)
                    a[k] = fmaf(m[u], bf16_to_f(v[u][k]), a[k]);
        }
        float sc = invdeg[w];
        ushort8v o;
#pragma unroll
        for (int k = 0; k < 8; ++k) o[k] = bf16_rne(a[k] * sc);
        *(ushort8v*)&hbuf[el * 264 + lane * 8] = o;
    }
    __syncthreads();
    {
        int sl = tid;                      // 0..511
        int k32 = sl >> 6, lt = sl & 63;
        int row = lt & 15, hi = lt >> 4;
        int k0 = k32 * 32 + hi * 8;
        ushort8v v = *(const ushort8v*)&hbuf[row * 264 + k0];
        nt_store8(Et + (((size_t)e16 * 8 + k32) << 9) + lt * 8, v);
    }
}

// ---- E->V mean + bias + relu -> row-major bf16; half-wave per node ----
__global__ __launch_bounds__(256) void agg_v256_row(
    const unsigned short* __restrict__ src, unsigned short* __restrict__ Vb,
    const int* __restrict__ cnt, const int* __restrict__ lists,
    const float* __restrict__ invdeg, const float* __restrict__ bias, int nseg)
{
    int w = (blockIdx.x * 256 + threadIdx.x) >> 5;
    int lane = threadIdx.x & 31;
    if (w >= nseg) return;
    int s = w * VSTRIDE, e = s + cnt[w];
    float a[8] = {};
    for (int j = s; j < e; j += 8) {
        int r[8]; float m[8];
        r[0] = lists[j]; m[0] = 1.f;
#pragma unroll
        for (int u = 1; u < 8; ++u) {
            bool ok = (j + u) < e;
            r[u] = ok ? lists[j + u] : r[0];
            m[u] = ok ? 1.f : 0.f;
        }
        ushort8v v[8];
#pragma unroll
        for (int u = 0; u < 8; ++u)
            v[u] = *(const ushort8v*)(src + (size_t)r[u] * 256 + lane * 8);
#pragma unroll
        for (int k = 0; k < 8; ++k) a[k] += bf16_to_f(v[0][k]);
#pragma unroll
        for (int u = 1; u < 8; ++u)
#pragma unroll
            for (int k = 0; k < 8; ++k)
                a[k] = fmaf(m[u], bf16_to_f(v[u][k]), a[k]);
    }
    float sc = invdeg[w];
    float4 b0 = *(const float4*)(bias + lane * 8);
    float4 b1 = *(const float4*)(bias + lane * 8 + 4);
    float bb[8] = { b0.x, b0.y, b0.z, b0.w, b1.x, b1.y, b1.z, b1.w };
    ushort8v o;
#pragma unroll
    for (int k = 0; k < 8; ++k) o[k] = bf16_rne(fmaxf(a[k] * sc + bb[k], 0.f));
    nt_store8(Vb + (size_t)w * 256 + lane * 8, o);
}

// ---- E->V mean + bias + relu -> fragment-tiled bf16; 512 thr, one node per half-wave ----
__global__ __launch_bounds__(512) void agg_v256_blk(
    const unsigned short* __restrict__ src, unsigned short* __restrict__ At,
    const int* __restrict__ cnt, const int* __restrict__ lists,
    const float* __restrict__ invdeg, const float* __restrict__ bias)
{
    __shared__ unsigned short hbuf[16 * 264];
    int tid = threadIdx.x, lane = tid & 31, hw = tid >> 5;   // hw: 0..15
    int m16 = blockIdx.x;
    float4 b0 = *(const float4*)(bias + lane * 8);
    float4 b1 = *(const float4*)(bias + lane * 8 + 4);
    float bb[8] = { b0.x, b0.y, b0.z, b0.w, b1.x, b1.y, b1.z, b1.w };
    {
        int nl = hw;
        int w = m16 * 16 + nl;
        int s = w * VSTRIDE, e = s + cnt[w];
        float a[8] = {};
        for (int j = s; j < e; j += 8) {
            int r[8]; float m[8];
            r[0] = lists[j]; m[0] = 1.f;
#pragma unroll
            for (int u = 1; u < 8; ++u) {
                bool ok = (j + u) < e;
                r[u] = ok ? lists[j + u] : r[0];
                m[u] = ok ? 1.f : 0.f;
            }
            ushort8v v[8];
#pragma unroll
            for (int u = 0; u < 8; ++u)
                v[u] = *(const ushort8v*)(src + (size_t)r[u] * 256 + lane * 8);
#pragma unroll
            for (int k = 0; k < 8; ++k) a[k] += bf16_to_f(v[0][k]);
#pragma unroll
            for (int u = 1; u < 8; ++u)
#pragma unroll
                for (int k = 0; k < 8; ++k)
                    a[k] = fmaf(m[u], bf16_to_f(v[u][k]), a[k]);
        }
        float sc = invdeg[w];
        ushort8v o;
#pragma unroll
        for (int k = 0; k < 8; ++k) o[k] = bf16_rne(fmaxf(a[k] * sc + bb[k], 0.f));
        *(ushort8v*)&hbuf[nl * 264 + lane * 8] = o;
    }
    __syncthreads();
    {
        int sl = tid;                      // 0..511
        int k32 = sl >> 6, lt = sl & 63;
        int row = lt & 15, hi = lt >> 4;
        int k0 = k32 * 32 + hi * 8;
        ushort8v v = *(const ushort8v*)&hbuf[row * 264 + k0];
        nt_store8(At + (((size_t)m16 * 8 + k32) << 9) + lt * 8, v);
    }
}

// ---- mean-aggregation, F=40 (edges), bf16 in, bf16 out, 8 in flight ----
__global__ __launch_bounds__(256) void agg_mean40(
    const unsigned short* __restrict__ src, unsigned short* __restrict__ dst,
    const int* __restrict__ cnt, const int* __restrict__ lists,
    const float* __restrict__ invdeg, int nseg)
{
    int w = (blockIdx.x * 256 + threadIdx.x) >> 6;
    int lane = threadIdx.x & 63;
    if (w >= nseg) return;
    int s = w * ESTRIDE, e = s + cnt[w];
    if (lane < 40) {
        float acc = 0.f;
        for (int j = s; j < e; j += 8) {
            int r[8]; float m[8];
            r[0] = lists[j]; m[0] = 1.f;
#pragma unroll
            for (int u = 1; u < 8; ++u) {
                bool ok = (j + u) < e;
                r[u] = ok ? lists[j + u] : r[0];
                m[u] = ok ? 1.f : 0.f;
            }
            float v[8];
#pragma unroll
            for (int u = 0; u < 8; ++u)
                v[u] = bf16_to_f(src[(size_t)r[u] * 40 + lane]);
            acc += v[0];
#pragma unroll
            for (int u = 1; u < 8; ++u) acc = fmaf(m[u], v[u], acc);
        }
        dst[(size_t)w * 40 + lane] = bf16_rne(acc * invdeg[w]);
    }
}

// ------- final E->V mean at F=40 + bias + log_softmax, wave per node -------
__global__ __launch_bounds__(256) void agg_v40_lsm(
    const unsigned short* __restrict__ efeat, float* __restrict__ out,
    const int* __restrict__ cnt, const int* __restrict__ lists,
    const float* __restrict__ invdeg, const float* __restrict__ bias,
    int nseg)
{
    int w = (blockIdx.x * 256 + threadIdx.x) >> 6;
    int lane = threadIdx.x & 63;
    if (w >= nseg) return;
    int s = w * VSTRIDE, e = s + cnt[w];
    float acc = 0.f;
    if (lane < 40) {
        for (int j = s; j < e; j += 4) {
            int r[4]; float m[4];
            r[0] = lists[j]; m[0] = 1.f;
#pragma unroll
            for (int u = 1; u < 4; ++u) {
                bool ok = (j + u) < e;
                r[u] = ok ? lists[j + u] : r[0];
                m[u] = ok ? 1.f : 0.f;
            }
            float v[4];
#pragma unroll
            for (int u = 0; u < 4; ++u)
                v[u] = bf16_to_f(efeat[(size_t)r[u] * 40 + lane]);
            acc += v[0];
#pragma unroll
            for (int u = 1; u < 4; ++u) acc = fmaf(m[u], v[u], acc);
        }
    }
    float val = (lane < 40) ? (acc * invdeg[w] + bias[lane]) : -1e30f;
    float m = val;
#pragma unroll
    for (int o = 32; o; o >>= 1) m = fmaxf(m, __shfl_xor(m, o));
    float ex = (lane < 40) ? expf(val - m) : 0.f;
    float ssum = ex;
#pragma unroll
    for (int o = 32; o; o >>= 1) ssum += __shfl_xor(ssum, o);
    if (lane < 40) out[(size_t)w * 40 + lane] = val - m - logf(ssum);
}

// ---------------- launch ----------------
extern "C" void kernel_launch(void* const* d_in, const int* in_sizes, int n_in,
                              void* d_out, int out_size, void* d_ws, size_t ws_size,
                              hipStream_t stream)
{
    const float* X        = (const float*)d_in[0];
    const int*   node_idx = (const int*)d_in[1];
    const int*   edge_idx = (const int*)d_in[2];
    const float* W1 = (const float*)d_in[3];
    const float* b1 = (const float*)d_in[4];
    const float* W2 = (const float*)d_in[5];
    const float* b2 = (const float*)d_in[6];
    const float* W3 = (const float*)d_in[7];
    const float* b3 = (const float*)d_in[8];
    float* out = (float*)d_out;

    char* p = (char*)d_ws;
    auto alloc = [&](size_t bytes) -> char* {
        char* r = p;
        p += (bytes + 255) & ~(size_t)255;
        return r;
    };
    int*   cnt_e = (int*)alloc((size_t)N_EDGES * 4);
    int*   cnt_v = (int*)alloc((size_t)N_NODES * 4);
    float* inv_e = (float*)alloc((size_t)N_EDGES * 4);
    float* inv_v = (float*)alloc((size_t)N_NODES * 4);
    unsigned* bhe = (unsigned*)alloc((size_t)NB_RANK * EW * 4);
    unsigned* bhv = (unsigned*)alloc((size_t)NB_RANK * VW * 4);
    unsigned* bbase_e = (unsigned*)alloc((size_t)NB_RANK * EW * 4);
    unsigned* bbase_v = (unsigned*)alloc((size_t)NB_RANK * VW * 4);
    unsigned char* lrank_e = (unsigned char*)alloc((size_t)NNZ_CT);
    unsigned char* lrank_v = (unsigned char*)alloc((size_t)NNZ_CT);
    int*   csr_e = (int*)alloc((size_t)N_EDGES * ESTRIDE * 4);
    int*   csr_v = (int*)alloc((size_t)N_NODES * VSTRIDE * 4);

    const int M16 = N_NODES / 16;              // 3125
    const int M16_PAD = 391 * 8;               // 3128 (GEMM-V grid coverage)
    const int E16 = N_EDGES / 16;              // 1250
    const int E16_PAD = 157 * 8;               // 1256 (GEMM-E grid coverage)
    unsigned short* Xb  = (unsigned short*)alloc((size_t)N_NODES * 256 * 2);
    unsigned short* At  = (unsigned short*)alloc((size_t)M16_PAD * 4096 * 2);
    unsigned short* Et  = (unsigned short*)alloc((size_t)E16_PAD * 4096 * 2);
    unsigned short* Ef  = (unsigned short*)alloc((size_t)N_EDGES * 256 * 2);
    unsigned short* W1h = (unsigned short*)alloc((size_t)16 * 4096 * 2);
    unsigned short* W1l = (unsigned short*)alloc((size_t)16 * 4096 * 2);
    unsigned short* W2h = (unsigned short*)alloc((size_t)16 * 4096 * 2);
    unsigned short* W2l = (unsigned short*)alloc((size_t)16 * 4096 * 2);
    unsigned short* W3h = (unsigned short*)alloc((size_t)8 * 4096 * 2);
    unsigned short* W3l = (unsigned short*)alloc((size_t)8 * 4096 * 2);
    unsigned short* C40 = (unsigned short*)alloc((size_t)N_NODES * 40 * 2);
    unsigned short* E40 = (unsigned short*)alloc((size_t)N_EDGES * 40 * 2);

    // CSR build: 512-thread LDS-hist ranks -> batched bases+cnt+inv+converts -> fixed-stride fill
    rank_lds<<<NB_RANK, 512, 0, stream>>>(node_idx, edge_idx, bhe, bhv, lrank_e, lrank_v);
    mid_fuse<<<6399, 256, 0, stream>>>(bhe, bhv, bbase_e, bbase_v, cnt_e, cnt_v, inv_e, inv_v,
                                       X, Xb, W1, W1h, W1l, W2, W2h, W2l, W3, W3h, W3l);
    fill_part<<<2048, 256, 0, stream>>>(node_idx, edge_idx, lrank_e, lrank_v,
                                        bbase_e, bbase_v, csr_e, csr_v);

    dim3 gE_gemm(2, 157);    // GEMM on 20000 edge rows
    dim3 gV_gemm(1, 391);    // GEMM on 50000 node rows (layer 3, 40 cols)
    const int gVhw = (N_NODES + 7) / 8;    // half-wave row kernel: 8 segs/block
    const int gEw = (N_EDGES + 3) / 4;
    const int gVw = (N_NODES + 3) / 4;

    // layer 1: V->E agg first (commutes with GEMM), GEMM on edges, E->V to row-major
    agg_e256_tiled<<<E16, 512, 0, stream>>>(Xb, Et, cnt_e, csr_e, inv_e);
    gemm_bf16<<<gE_gemm, 256, 0, stream>>>(Et, W1h, W1l, Ef, N_EDGES, 256, 256);
    agg_v256_row<<<gVhw, 256, 0, stream>>>(Ef, Xb, cnt_v, csr_v, inv_v, b1, N_NODES);

    // layer 2: same; E->V writes tiled (feeds layer-3 GEMM-V)
    agg_e256_tiled<<<E16, 512, 0, stream>>>(Xb, Et, cnt_e, csr_e, inv_e);
    gemm_bf16<<<gE_gemm, 256, 0, stream>>>(Et, W2h, W2l, Ef, N_EDGES, 256, 256);
    agg_v256_blk<<<M16, 512, 0, stream>>>(Ef, At, cnt_v, csr_v, inv_v, b2);

    // layer 3: GEMM-V to 40 cols, then 40-dim aggs + log_softmax
    gemm_bf16<<<gV_gemm, 256, 0, stream>>>(At, W3h, W3l, C40, N_NODES, 40, 40);
    agg_mean40<<<gEw, 256, 0, stream>>>(C40, E40, cnt_e, csr_e, inv_e, N_EDGES);
    agg_v40_lsm<<<gVw, 256, 0, stream>>>(E40, out, cnt_v, csr_v, inv_v, b3, N_NODES);
    (void)in_sizes; (void)n_in; (void)out_size; (void)ws_size;
}